// Round 1
// baseline (132.959 us; speedup 1.0000x reference)
//
#include <hip/hip_runtime.h>
#include <cstdint>
#include <cstddef>

// Problem constants
#define B_DIM 4096   // batch (GEMM M)
#define S_DIM 2048   // states (GEMM N)
#define D_DIM 2496   // feature dim (GEMM K)
#define QSCALE 127.0f
#define QSCALE2 16129.0f   // 127^2

// R7: 2-phase pipelined double-buffer (T3 minimum recipe, m230/m248v2):
// issue next-tile staging BEFORE computing the current tile, one
// vmcnt(0)+barrier per K-step at the END. The drain (R5/R6's measured wall)
// now overlaps the full MFMA phase instead of serializing against it.
// Tile grows to 128x256 (8 waves) -> 256 blocks = 1/CU, 25% less staging
// traffic, dbuf LDS 48 KB stays under the 64 KB static limit.
#define BM 128
#define BN 256
#define BK 64
#define KITERS (D_DIM / BK)        // 39
#define BUFB ((BM + BN) * BK)      // 24576 B per buffer (A 8 KB | B 16 KB)

typedef __attribute__((ext_vector_type(4))) int int4v;

// ---------------------------------------------------------------------------
struct __attribute__((aligned(8))) uc8 { unsigned char c[8]; };

// Prep, wave-per-row: quantize one row to u8 in [0,127] (RTN) and compute the
// EXACT fp32 squared norm of the original floats via shuffle reduce.
__global__ __launch_bounds__(256) void prep_kernel(
    const float* __restrict__ X, const float* __restrict__ Mx,
    unsigned char* __restrict__ Xq, unsigned char* __restrict__ Mq,
    float* __restrict__ xsq, float* __restrict__ msq)
{
    const int lane = threadIdx.x & 63;
    const int row  = blockIdx.x * 4 + (threadIdx.x >> 6);

    const float* src; unsigned char* dst; float* sq;
    if (row < B_DIM) {
        src = X + (size_t)row * D_DIM; dst = Xq + (size_t)row * D_DIM; sq = xsq + row;
    } else {
        const int r = row - B_DIM;
        src = Mx + (size_t)r * D_DIM; dst = Mq + (size_t)r * D_DIM; sq = msq + r;
    }

    const float4* s4 = (const float4*)src;
    uc8* d8 = (uc8*)dst;
    float acc = 0.f;
    for (int i = lane; i < D_DIM / 8; i += 64) {
        float4 a = s4[2 * i], b = s4[2 * i + 1];
        acc += a.x * a.x + a.y * a.y + a.z * a.z + a.w * a.w;
        acc += b.x * b.x + b.y * b.y + b.z * b.z + b.w * b.w;
        uc8 q;
        q.c[0] = (unsigned char)__float2int_rn(a.x * QSCALE);
        q.c[1] = (unsigned char)__float2int_rn(a.y * QSCALE);
        q.c[2] = (unsigned char)__float2int_rn(a.z * QSCALE);
        q.c[3] = (unsigned char)__float2int_rn(a.w * QSCALE);
        q.c[4] = (unsigned char)__float2int_rn(b.x * QSCALE);
        q.c[5] = (unsigned char)__float2int_rn(b.y * QSCALE);
        q.c[6] = (unsigned char)__float2int_rn(b.z * QSCALE);
        q.c[7] = (unsigned char)__float2int_rn(b.w * QSCALE);
        d8[i] = q;
    }
    #pragma unroll
    for (int off = 32; off > 0; off >>= 1)
        acc += __shfl_down(acc, off, 64);
    if (lane == 0) *sq = acc;
}

// ---------------------------------------------------------------------------
// global -> LDS direct (async) load, 16 B per lane; dest = wave-uniform base +
// lane*16, i.e. one issue fills 1024 contiguous LDS bytes (16 rows x 64 B).
__device__ __forceinline__ void gld_lds16(const unsigned char* g, unsigned char* l) {
    __builtin_amdgcn_global_load_lds(
        (const __attribute__((address_space(1))) unsigned int*)g,
        (__attribute__((address_space(3))) unsigned int*)l,
        16, 0, 0);
}

// ---------------------------------------------------------------------------
// C[row,col] = (2*cross - xsq[row] - msq[col]) / 500, cross = acc_i32/127^2.
// A: [4096, 2496] u8 row-major; Bt: [2048, 2496] u8 row-major (NT GEMM).
//
// LDS: chunks of 16 rows x 64 k-bytes = 1024 B (matches gld_lds16's
// contiguous landing zone: lane l -> row l>>2, byte (l&3)*16). Fragment
// reads at row*64 stride are bank-balanced (R5-verified profile).
// Per buffer: A chunks 0..7 (rowblocks of 128 rows), B chunks 0..15 (256).
__global__ __launch_bounds__(512) void gemm_kernel(
    const unsigned char* __restrict__ A,
    const unsigned char* __restrict__ Bt,
    const float* __restrict__ xsq, const float* __restrict__ msq,
    float* __restrict__ C)
{
    constexpr int N = S_DIM;
    constexpr int K = D_DIM;   // bytes per row

    __shared__ __align__(16) unsigned char lds[2 * BUFB];  // 48 KB double buffer

    const int tid  = threadIdx.x;
    const int lane = tid & 63;
    const int wave = tid >> 6;       // 8 waves
    const int wm = wave >> 2;        // wave row (0..1) -> 64 rows
    const int wn = wave & 3;         // wave col (0..3) -> 64 cols
    // XCD-aware bijective swizzle: 256 blocks, 8 XCDs; each XCD gets a
    // contiguous 4(bm) x 8(bn) region -> per-XCD working set 6.25 MB.
    const int bid = blockIdx.x;
    const int swz = (bid & 7) * 32 + (bid >> 3);
    const int bm  = swz >> 3;        // 0..31
    const int bn  = swz & 7;         // 0..7

    // Staging: per iter each wave issues 3 gld_lds16 (1 A chunk, 2 B chunks).
    // A: wave w -> rows bm*128 + w*16 + srow.
    // B: wave w -> rows bn*256 + w*32 + {0,16} + srow.
    const int srow  = lane >> 2;
    const int sbyte = (lane & 3) * 16;
    const unsigned char* gA = A  + (size_t)(bm * BM + wave * 16 + srow) * K + sbyte;
    const unsigned char* gB = Bt + (size_t)(bn * BN + wave * 32 + srow) * K + sbyte;
    unsigned char* lA = lds + wave * 1024;             // A chunk w   (buf 0)
    unsigned char* lB = lds + BM * BK + wave * 2048;   // B chunks 2w (buf 0)

    int4v acc[4][4] = {};

    // i8 16x16x64 A/B fragment (verified R5): m (or n) = lane&15,
    // k = (lane>>4)*16 + j. One ds_read_b128 per fragment.
    const int ko = (lane >> 4) * 16;
    const int fr = lane & 15;

    // Prologue: stage tile 0 into buffer 0, drain, barrier.
    gld_lds16(gA, lA);
    gld_lds16(gB, lB);
    gld_lds16(gB + (size_t)16 * K, lB + 1024);
    __syncthreads();

    for (int t = 0; t < KITERS; ++t) {   // 39 iterations
        const int cb = (t & 1) * BUFB;   // compute buffer
        const int nb = cb ^ BUFB;        // stage buffer

        // Issue next tile's staging FIRST — lands during the MFMA phase.
        // (buf nb was fully consumed in iter t-1; barrier at end of t-1
        // makes the overwrite safe.)
        if (t + 1 < KITERS) {
            const int go = (t + 1) * BK;
            gld_lds16(gA + go,                  lA + nb);
            gld_lds16(gB + go,                  lB + nb);
            gld_lds16(gB + (size_t)16 * K + go, lB + nb + 1024);
        }

        // Compute current tile (one 64-byte k-window).
        const unsigned char* As = lds + cb;
        const unsigned char* Bs = lds + cb + BM * BK;
        int4v af[4], bf[4];
        #pragma unroll
        for (int i = 0; i < 4; ++i) {
            // row m = wm*64 + i*16 + fr -> A chunk wm*4+i, row_local fr
            af[i] = *(const int4v*)&As[(wm * 4 + i) * 1024 + fr * 64 + ko];
            // col n = wn*64 + i*16 + fr -> B chunk wn*4+i
            bf[i] = *(const int4v*)&Bs[(wn * 4 + i) * 1024 + fr * 64 + ko];
        }
        #pragma unroll
        for (int mi = 0; mi < 4; ++mi)
            #pragma unroll
            for (int ni = 0; ni < 4; ++ni)
                acc[mi][ni] = __builtin_amdgcn_mfma_i32_16x16x64_i8(
                    af[mi], bf[ni], acc[mi][ni], 0, 0, 0);

        // Single barrier per K-step: its vmcnt(0) waits on tile t+1's loads,
        // which have had the whole compute phase to land (overlapped drain).
        __syncthreads();
    }

    // Epilogue. C/D layout dtype-independent (m121-m128): col = lane&15,
    // row = (lane>>4)*4 + reg. cross = acc/127^2 in fp32.
    const int row0 = bm * BM + wm * 64 + (lane >> 4) * 4;
    const int col0 = bn * BN + wn * 64 + fr;
    float ms[4];
    #pragma unroll
    for (int ni = 0; ni < 4; ++ni) ms[ni] = msq[col0 + ni * 16];
    #pragma unroll
    for (int mi = 0; mi < 4; ++mi) {
        #pragma unroll
        for (int r = 0; r < 4; ++r) {
            const int row = row0 + mi * 16 + r;
            const float xs = xsq[row];
            #pragma unroll
            for (int ni = 0; ni < 4; ++ni) {
                const float cr2 = (float)acc[mi][ni][r] * (2.0f / QSCALE2);
                const float v = (cr2 - xs - ms[ni]) * (1.0f / 500.0f);
                C[(size_t)row * N + col0 + ni * 16] = v;
            }
        }
    }
}

// ---------------------------------------------------------------------------
extern "C" void kernel_launch(void* const* d_in, const int* in_sizes, int n_in,
                              void* d_out, int out_size, void* d_ws, size_t ws_size,
                              hipStream_t stream) {
    const float* X  = (const float*)d_in[0];  // [4096, 2496]
    const float* Mx = (const float*)d_in[1];  // [2048, 2496]
    float* out = (float*)d_out;               // [4096, 2048]

    // Workspace layout (~15.4 MB): Xq u8 | Mq u8 | xsq f32 | msq f32
    unsigned char* Xq = (unsigned char*)d_ws;
    unsigned char* Mq = Xq + (size_t)B_DIM * D_DIM;
    float* xsq = (float*)(Mq + (size_t)S_DIM * D_DIM);
    float* msq = xsq + B_DIM;

    prep_kernel<<<(B_DIM + S_DIM) / 4, 256, 0, stream>>>(X, Mx, Xq, Mq, xsq, msq);

    dim3 grid(256);  // 32 bm x 8 bn, 1 block/CU
    gemm_kernel<<<grid, 512, 0, stream>>>(Xq, Mq, xsq, msq, out);
}

// Round 2
// 128.686 us; speedup vs baseline: 1.0332x; 1.0332x over previous
//
#include <hip/hip_runtime.h>
#include <cstdint>
#include <cstddef>

// Problem constants
#define B_DIM 4096   // batch (GEMM M)
#define S_DIM 2048   // states (GEMM N)
#define D_DIM 2496   // feature dim (GEMM K)
#define QSCALE 127.0f
#define QSCALE2 16129.0f   // 127^2

// R8: two fixes from the R7 post-mortem.
// (1) Slot-major chunk layout: the fragment ds_read_b128 at fr*64+ko was an
//     8-way bank conflict per quarter-wave (lanes 0-15 at 64B stride -> banks
//     {0,16} only; ~2.9x per m136) — the real reason gemm sat at ~40us and
//     why R7's staging overlap bought nothing (LDS read was the critical
//     path; T2 regime-gate, m252). Since WE write the quantized arrays, prep
//     now emits each 16-row x 64-B chunk slot-major so gld_lds16's linear
//     fill (base + lane*16) IS the fragment layout: reads become
//     addr = chunkbase + lane*16 — linear, conflict-free by construction
//     (rule #21: swizzle source + read together, LDS dest stays linear).
// (2) Counted-vmcnt 3-buffer pipeline (T3+T4 minimum): stage(t+2) after the
//     barrier, wait vmcnt(4) (own 4 loads for tile t) before it, never 0 in
//     the main loop. 128x128 / 4 waves / 512 blocks restores 2 blocks/CU.
#define BM 128
#define BN 128
#define BK 64
#define KITERS (D_DIM / BK)   // 39 k-chunks of 64 bytes
#define BUFB ((BM + BN) * BK) // 16384 B per buffer (A 8 KB | B 8 KB)

typedef __attribute__((ext_vector_type(4))) int int4v;

// ---------------------------------------------------------------------------
struct __attribute__((aligned(8))) uc8 { unsigned char c[8]; };

// Prep, wave-per-row: quantize one row to u8 in [0,127] (RTN), EXACT fp32
// squared norm via shuffle reduce. Output layout (per array): chunks of
// 16 rows x 64 k-bytes, chunkbase = (rowblock*39 + kchunk)*1024, and WITHIN
// a chunk slot-major: offset = ((k>>4)&3)*256 + (row&15)*16 + (k&15).
// This makes a linear 1024-B copy of a chunk land in LDS such that
// lane*16 = the i8 16x16x64 fragment (m=lane&15, k16slot=lane>>4).
__global__ __launch_bounds__(256) void prep_kernel(
    const float* __restrict__ X, const float* __restrict__ Mx,
    unsigned char* __restrict__ Xq, unsigned char* __restrict__ Mq,
    float* __restrict__ xsq, float* __restrict__ msq)
{
    const int lane = threadIdx.x & 63;
    const int row  = blockIdx.x * 4 + (threadIdx.x >> 6);

    const float* src; unsigned char* dstbase; float* sq;
    if (row < B_DIM) {
        src = X + (size_t)row * D_DIM;
        dstbase = Xq + (size_t)(row >> 4) * (KITERS * 1024) + (row & 15) * 16;
        sq = xsq + row;
    } else {
        const int r = row - B_DIM;
        src = Mx + (size_t)r * D_DIM;
        dstbase = Mq + (size_t)(r >> 4) * (KITERS * 1024) + (r & 15) * 16;
        sq = msq + r;
    }

    const float4* s4 = (const float4*)src;
    float acc = 0.f;
    for (int i = lane; i < D_DIM / 8; i += 64) {   // i indexes 8-byte k-groups
        float4 a = s4[2 * i], b = s4[2 * i + 1];
        acc += a.x * a.x + a.y * a.y + a.z * a.z + a.w * a.w;
        acc += b.x * b.x + b.y * b.y + b.z * b.z + b.w * b.w;
        uc8 q;
        q.c[0] = (unsigned char)__float2int_rn(a.x * QSCALE);
        q.c[1] = (unsigned char)__float2int_rn(a.y * QSCALE);
        q.c[2] = (unsigned char)__float2int_rn(a.z * QSCALE);
        q.c[3] = (unsigned char)__float2int_rn(a.w * QSCALE);
        q.c[4] = (unsigned char)__float2int_rn(b.x * QSCALE);
        q.c[5] = (unsigned char)__float2int_rn(b.y * QSCALE);
        q.c[6] = (unsigned char)__float2int_rn(b.z * QSCALE);
        q.c[7] = (unsigned char)__float2int_rn(b.w * QSCALE);
        // k = i*8: kchunk = i>>3, slot = (i>>1)&3, byte-in-slot = (i&1)*8
        *(uc8*)(dstbase + (i >> 3) * 1024 + ((i >> 1) & 3) * 256 + (i & 1) * 8) = q;
    }
    #pragma unroll
    for (int off = 32; off > 0; off >>= 1)
        acc += __shfl_down(acc, off, 64);
    if (lane == 0) *sq = acc;
}

// ---------------------------------------------------------------------------
// global -> LDS direct (async) load, 16 B per lane; dest = wave-uniform base +
// lane*16. Source is per-lane (we pass base + lane*16 -> contiguous 1 KB).
__device__ __forceinline__ void gld_lds16(const unsigned char* g, unsigned char* l) {
    __builtin_amdgcn_global_load_lds(
        (const __attribute__((address_space(1))) unsigned int*)g,
        (__attribute__((address_space(3))) unsigned int*)l,
        16, 0, 0);
}

// ---------------------------------------------------------------------------
__global__ __launch_bounds__(256) void gemm_kernel(
    const unsigned char* __restrict__ A,   // slot-major chunked [256 rb][39 kc][1024]
    const unsigned char* __restrict__ Bt,  // slot-major chunked [128 rb][39 kc][1024]
    const float* __restrict__ xsq, const float* __restrict__ msq,
    float* __restrict__ C)
{
    constexpr int N = S_DIM;

    __shared__ __align__(16) unsigned char lds[3 * BUFB];  // 48 KB, 3 buffers

    const int tid  = threadIdx.x;
    const int lane = tid & 63;
    const int wave = tid >> 6;       // 4 waves, 2x2 of 64x64
    const int wm = wave >> 1;
    const int wn = wave & 1;

    // XCD-aware bijective swizzle: 512 blocks, 8 XCDs, each gets a compact
    // 8(bm) x 8(bn) region (A 2.5 MB + B 2.5 MB working set).
    const int bid = blockIdx.x;
    const int xcd = bid & 7;
    const int lcl = bid >> 3;                  // 0..63
    const int bm  = (xcd >> 1) * 8 + (lcl >> 3);  // 0..31
    const int bn  = (xcd & 1) * 8 + (lcl & 7);    // 0..15

    // Staging: per K-step each wave copies 4 chunks (A rowblocks 2w,2w+1 and
    // B rowblocks 2w,2w+1), each a contiguous 1 KB at base + lane*16.
    const unsigned char* pA0 = A  + (size_t)((bm * 8 + 2 * wave    ) * KITERS) * 1024 + lane * 16;
    const unsigned char* pA1 = A  + (size_t)((bm * 8 + 2 * wave + 1) * KITERS) * 1024 + lane * 16;
    const unsigned char* pB0 = Bt + (size_t)((bn * 8 + 2 * wave    ) * KITERS) * 1024 + lane * 16;
    const unsigned char* pB1 = Bt + (size_t)((bn * 8 + 2 * wave + 1) * KITERS) * 1024 + lane * 16;
    const int dA0 = (2 * wave) * 1024;            // LDS offsets within buffer
    const int dA1 = dA0 + 1024;
    const int dB0 = 8192 + (2 * wave) * 1024;
    const int dB1 = dB0 + 1024;

    int4v acc[4][4] = {};

    // Fragment read offsets: linear lane*16 within each chunk (conflict-free).
    const int aoff = wm * 4096 + lane * 16;
    const int boff = 8192 + wn * 4096 + lane * 16;

#define STAGE(BUF) do { \
    gld_lds16(pA0, &lds[(BUF) + dA0]); \
    gld_lds16(pA1, &lds[(BUF) + dA1]); \
    gld_lds16(pB0, &lds[(BUF) + dB0]); \
    gld_lds16(pB1, &lds[(BUF) + dB1]); \
    pA0 += 1024; pA1 += 1024; pB0 += 1024; pB1 += 1024; \
} while (0)

#define COMPUTE(BUF) do { \
    int4v af[4], bf[4]; \
    _Pragma("unroll") \
    for (int i = 0; i < 4; ++i) { \
        af[i] = *(const int4v*)&lds[(BUF) + aoff + i * 1024]; \
        bf[i] = *(const int4v*)&lds[(BUF) + boff + i * 1024]; \
    } \
    _Pragma("unroll") \
    for (int mi = 0; mi < 4; ++mi) \
        _Pragma("unroll") \
        for (int ni = 0; ni < 4; ++ni) \
            acc[mi][ni] = __builtin_amdgcn_mfma_i32_16x16x64_i8( \
                af[mi], bf[ni], acc[mi][ni], 0, 0, 0); \
} while (0)

// One step: wait own 4 loads for the tile about to be computed (4 newer stay
// in flight), publish via barrier, then stage tile t+2 into the buffer that
// was computed at t-1 (safe: everyone passed the barrier after computing it),
// then compute tile t.
#define STEP(CBUF, SBUF) do { \
    asm volatile("s_waitcnt vmcnt(4)" ::: "memory"); \
    __builtin_amdgcn_s_barrier(); \
    STAGE(SBUF); \
    COMPUTE(CBUF); \
} while (0)

    // Prologue: tiles 0 and 1 in flight (8 loads/wave).
    STAGE(0);
    STAGE(BUFB);

    // Main loop: tiles 0..35 (12 x 3, fully static buffer refs), then 36.
    for (int t = 0; t < 36; t += 3) {
        STEP(0,        2 * BUFB);
        STEP(BUFB,     0       );
        STEP(2 * BUFB, BUFB    );
    }
    STEP(0, 2 * BUFB);   // t=36: stages tile 38 (last), computes tile 36

    // t=37: tile 38's 4 loads still in flight.
    asm volatile("s_waitcnt vmcnt(4)" ::: "memory");
    __builtin_amdgcn_s_barrier();
    COMPUTE(BUFB);
    // t=38: drain.
    asm volatile("s_waitcnt vmcnt(0)" ::: "memory");
    __builtin_amdgcn_s_barrier();
    COMPUTE(2 * BUFB);

#undef STEP
#undef COMPUTE
#undef STAGE

    // Epilogue (verified R5 mapping, dtype-independent): col = lane&15,
    // row = (lane>>4)*4 + reg. cross = acc/127^2; C = (2*cross - xs - ms)/500.
    const int fr   = lane & 15;
    const int row0 = bm * BM + wm * 64 + (lane >> 4) * 4;
    const int col0 = bn * BN + wn * 64 + fr;
    float ms[4];
    #pragma unroll
    for (int ni = 0; ni < 4; ++ni) ms[ni] = msq[col0 + ni * 16];
    #pragma unroll
    for (int mi = 0; mi < 4; ++mi) {
        #pragma unroll
        for (int r = 0; r < 4; ++r) {
            const int row = row0 + mi * 16 + r;
            const float xs = xsq[row];
            #pragma unroll
            for (int ni = 0; ni < 4; ++ni) {
                const float cr2 = (float)acc[mi][ni][r] * (2.0f / QSCALE2);
                const float v = (cr2 - xs - ms[ni]) * (1.0f / 500.0f);
                C[(size_t)row * N + col0 + ni * 16] = v;
            }
        }
    }
}

// ---------------------------------------------------------------------------
extern "C" void kernel_launch(void* const* d_in, const int* in_sizes, int n_in,
                              void* d_out, int out_size, void* d_ws, size_t ws_size,
                              hipStream_t stream) {
    const float* X  = (const float*)d_in[0];  // [4096, 2496]
    const float* Mx = (const float*)d_in[1];  // [2048, 2496]
    float* out = (float*)d_out;               // [4096, 2048]

    // Workspace layout (~15.4 MB): Xq u8 | Mq u8 | xsq f32 | msq f32
    unsigned char* Xq = (unsigned char*)d_ws;
    unsigned char* Mq = Xq + (size_t)B_DIM * D_DIM;
    float* xsq = (float*)(Mq + (size_t)S_DIM * D_DIM);
    float* msq = xsq + B_DIM;

    prep_kernel<<<(B_DIM + S_DIM) / 4, 256, 0, stream>>>(X, Mx, Xq, Mq, xsq, msq);

    dim3 grid(512);  // 32 bm x 16 bn, 2 blocks/CU
    gemm_kernel<<<grid, 256, 0, stream>>>(Xq, Mq, xsq, msq, out);
}

// Round 3
// 127.889 us; speedup vs baseline: 1.0396x; 1.0062x over previous
//
#include <hip/hip_runtime.h>
#include <cstdint>
#include <cstddef>

// Problem constants
#define B_DIM 4096   // batch (GEMM M)
#define S_DIM 2048   // states (GEMM N)
#define D_DIM 2496   // feature dim (GEMM K)
#define QSCALE 127.0f
#define QSCALE2 16129.0f   // 127^2

// R9: R7/R8 post-mortem — two radical pipeline/layout rewrites moved
// end-to-end by <5 us, falsifying the LDS-conflict and drain theories.
// Remaining candidate for the gemm's ~30 us: FETCH-bound tile re-reads.
// All prior mappings let one A-chunk be shared by 8 drifting blocks within
// an XCD (4 MiB L2): drift -> refetch from L3, degenerating to the all-miss
// staging bound (~327 MB). Fix is mapping-only: per XCD a 32bm x 2bn region.
//  - B panel per XCD = 2 x 128 cols x 2496 B = 0.64 MB: L2-RESIDENT for the
//    whole kernel -> B fetch is compulsory-only, drift-immune.
//  - A-chunk shared by exactly 2 adjacently-launched blocks (l&1 pair) ->
//    minimal drift window; worst-case fetch bounded at ~168 MB, best ~87 MB.
// Everything else (slot-major chunks, counted-vmcnt 3-buffer pipeline,
// epilogue) is byte-identical to R8 for clean attribution.
#define BM 128
#define BN 128
#define BK 64
#define KITERS (D_DIM / BK)   // 39 k-chunks of 64 bytes
#define BUFB ((BM + BN) * BK) // 16384 B per buffer (A 8 KB | B 8 KB)

typedef __attribute__((ext_vector_type(4))) int int4v;

// ---------------------------------------------------------------------------
struct __attribute__((aligned(8))) uc8 { unsigned char c[8]; };

// Prep, wave-per-row: quantize one row to u8 in [0,127] (RTN), EXACT fp32
// squared norm via shuffle reduce. Output layout (per array): chunks of
// 16 rows x 64 k-bytes, chunkbase = (rowblock*39 + kchunk)*1024, and WITHIN
// a chunk slot-major: offset = ((k>>4)&3)*256 + (row&15)*16 + (k&15).
// This makes a linear 1024-B copy of a chunk land in LDS such that
// lane*16 = the i8 16x16x64 fragment (m=lane&15, k16slot=lane>>4).
__global__ __launch_bounds__(256) void prep_kernel(
    const float* __restrict__ X, const float* __restrict__ Mx,
    unsigned char* __restrict__ Xq, unsigned char* __restrict__ Mq,
    float* __restrict__ xsq, float* __restrict__ msq)
{
    const int lane = threadIdx.x & 63;
    const int row  = blockIdx.x * 4 + (threadIdx.x >> 6);

    const float* src; unsigned char* dstbase; float* sq;
    if (row < B_DIM) {
        src = X + (size_t)row * D_DIM;
        dstbase = Xq + (size_t)(row >> 4) * (KITERS * 1024) + (row & 15) * 16;
        sq = xsq + row;
    } else {
        const int r = row - B_DIM;
        src = Mx + (size_t)r * D_DIM;
        dstbase = Mq + (size_t)(r >> 4) * (KITERS * 1024) + (r & 15) * 16;
        sq = msq + r;
    }

    const float4* s4 = (const float4*)src;
    float acc = 0.f;
    for (int i = lane; i < D_DIM / 8; i += 64) {   // i indexes 8-byte k-groups
        float4 a = s4[2 * i], b = s4[2 * i + 1];
        acc += a.x * a.x + a.y * a.y + a.z * a.z + a.w * a.w;
        acc += b.x * b.x + b.y * b.y + b.z * b.z + b.w * b.w;
        uc8 q;
        q.c[0] = (unsigned char)__float2int_rn(a.x * QSCALE);
        q.c[1] = (unsigned char)__float2int_rn(a.y * QSCALE);
        q.c[2] = (unsigned char)__float2int_rn(a.z * QSCALE);
        q.c[3] = (unsigned char)__float2int_rn(a.w * QSCALE);
        q.c[4] = (unsigned char)__float2int_rn(b.x * QSCALE);
        q.c[5] = (unsigned char)__float2int_rn(b.y * QSCALE);
        q.c[6] = (unsigned char)__float2int_rn(b.z * QSCALE);
        q.c[7] = (unsigned char)__float2int_rn(b.w * QSCALE);
        // k = i*8: kchunk = i>>3, slot = (i>>1)&3, byte-in-slot = (i&1)*8
        *(uc8*)(dstbase + (i >> 3) * 1024 + ((i >> 1) & 3) * 256 + (i & 1) * 8) = q;
    }
    #pragma unroll
    for (int off = 32; off > 0; off >>= 1)
        acc += __shfl_down(acc, off, 64);
    if (lane == 0) *sq = acc;
}

// ---------------------------------------------------------------------------
// global -> LDS direct (async) load, 16 B per lane; dest = wave-uniform base +
// lane*16. Source is per-lane (we pass base + lane*16 -> contiguous 1 KB).
__device__ __forceinline__ void gld_lds16(const unsigned char* g, unsigned char* l) {
    __builtin_amdgcn_global_load_lds(
        (const __attribute__((address_space(1))) unsigned int*)g,
        (__attribute__((address_space(3))) unsigned int*)l,
        16, 0, 0);
}

// ---------------------------------------------------------------------------
__global__ __launch_bounds__(256) void gemm_kernel(
    const unsigned char* __restrict__ A,   // slot-major chunked [256 rb][39 kc][1024]
    const unsigned char* __restrict__ Bt,  // slot-major chunked [128 rb][39 kc][1024]
    const float* __restrict__ xsq, const float* __restrict__ msq,
    float* __restrict__ C)
{
    constexpr int N = S_DIM;

    __shared__ __align__(16) unsigned char lds[3 * BUFB];  // 48 KB, 3 buffers

    const int tid  = threadIdx.x;
    const int lane = tid & 63;
    const int wave = tid >> 6;       // 4 waves, 2x2 of 64x64
    const int wm = wave >> 1;
    const int wn = wave & 1;

    // B-panel-resident XCD mapping: 512 blocks round-robin XCDs (xcd=bid&7,
    // m09). Each XCD gets region 32bm x 2bn:
    //   bn = 2*xcd + (l&1)  -> B panel 0.64 MB, L2-resident all kernel.
    //   bm = l>>1           -> A-chunk shared by exactly the adjacent l-pair.
    const int bid = blockIdx.x;
    const int xcd = bid & 7;
    const int l   = bid >> 3;              // 0..63 within XCD
    const int bm  = l >> 1;                // 0..31
    const int bn  = xcd * 2 + (l & 1);     // 0..15

    // Staging: per K-step each wave copies 4 chunks (A rowblocks 2w,2w+1 and
    // B rowblocks 2w,2w+1), each a contiguous 1 KB at base + lane*16.
    const unsigned char* pA0 = A  + (size_t)((bm * 8 + 2 * wave    ) * KITERS) * 1024 + lane * 16;
    const unsigned char* pA1 = A  + (size_t)((bm * 8 + 2 * wave + 1) * KITERS) * 1024 + lane * 16;
    const unsigned char* pB0 = Bt + (size_t)((bn * 8 + 2 * wave    ) * KITERS) * 1024 + lane * 16;
    const unsigned char* pB1 = Bt + (size_t)((bn * 8 + 2 * wave + 1) * KITERS) * 1024 + lane * 16;
    const int dA0 = (2 * wave) * 1024;            // LDS offsets within buffer
    const int dA1 = dA0 + 1024;
    const int dB0 = 8192 + (2 * wave) * 1024;
    const int dB1 = dB0 + 1024;

    int4v acc[4][4] = {};

    // Fragment read offsets: linear lane*16 within each chunk (conflict-free).
    const int aoff = wm * 4096 + lane * 16;
    const int boff = 8192 + wn * 4096 + lane * 16;

#define STAGE(BUF) do { \
    gld_lds16(pA0, &lds[(BUF) + dA0]); \
    gld_lds16(pA1, &lds[(BUF) + dA1]); \
    gld_lds16(pB0, &lds[(BUF) + dB0]); \
    gld_lds16(pB1, &lds[(BUF) + dB1]); \
    pA0 += 1024; pA1 += 1024; pB0 += 1024; pB1 += 1024; \
} while (0)

#define COMPUTE(BUF) do { \
    int4v af[4], bf[4]; \
    _Pragma("unroll") \
    for (int i = 0; i < 4; ++i) { \
        af[i] = *(const int4v*)&lds[(BUF) + aoff + i * 1024]; \
        bf[i] = *(const int4v*)&lds[(BUF) + boff + i * 1024]; \
    } \
    _Pragma("unroll") \
    for (int mi = 0; mi < 4; ++mi) \
        _Pragma("unroll") \
        for (int ni = 0; ni < 4; ++ni) \
            acc[mi][ni] = __builtin_amdgcn_mfma_i32_16x16x64_i8( \
                af[mi], bf[ni], acc[mi][ni], 0, 0, 0); \
} while (0)

// One step: wait own 4 loads for the tile about to be computed (4 newer stay
// in flight), publish via barrier, then stage tile t+2 into the buffer that
// was computed at t-1 (safe: everyone passed the barrier after computing it),
// then compute tile t.
#define STEP(CBUF, SBUF) do { \
    asm volatile("s_waitcnt vmcnt(4)" ::: "memory"); \
    __builtin_amdgcn_s_barrier(); \
    STAGE(SBUF); \
    COMPUTE(CBUF); \
} while (0)

    // Prologue: tiles 0 and 1 in flight (8 loads/wave).
    STAGE(0);
    STAGE(BUFB);

    // Main loop: tiles 0..35 (12 x 3, fully static buffer refs), then 36.
    for (int t = 0; t < 36; t += 3) {
        STEP(0,        2 * BUFB);
        STEP(BUFB,     0       );
        STEP(2 * BUFB, BUFB    );
    }
    STEP(0, 2 * BUFB);   // t=36: stages tile 38 (last), computes tile 36

    // t=37: tile 38's 4 loads still in flight.
    asm volatile("s_waitcnt vmcnt(4)" ::: "memory");
    __builtin_amdgcn_s_barrier();
    COMPUTE(BUFB);
    // t=38: drain.
    asm volatile("s_waitcnt vmcnt(0)" ::: "memory");
    __builtin_amdgcn_s_barrier();
    COMPUTE(2 * BUFB);

#undef STEP
#undef COMPUTE
#undef STAGE

    // Epilogue (verified R5 mapping, dtype-independent): col = lane&15,
    // row = (lane>>4)*4 + reg. cross = acc/127^2; C = (2*cross - xs - ms)/500.
    const int fr   = lane & 15;
    const int row0 = bm * BM + wm * 64 + (lane >> 4) * 4;
    const int col0 = bn * BN + wn * 64 + fr;
    float ms[4];
    #pragma unroll
    for (int ni = 0; ni < 4; ++ni) ms[ni] = msq[col0 + ni * 16];
    #pragma unroll
    for (int mi = 0; mi < 4; ++mi) {
        #pragma unroll
        for (int r = 0; r < 4; ++r) {
            const int row = row0 + mi * 16 + r;
            const float xs = xsq[row];
            #pragma unroll
            for (int ni = 0; ni < 4; ++ni) {
                const float cr2 = (float)acc[mi][ni][r] * (2.0f / QSCALE2);
                const float v = (cr2 - xs - ms[ni]) * (1.0f / 500.0f);
                C[(size_t)row * N + col0 + ni * 16] = v;
            }
        }
    }
}

// ---------------------------------------------------------------------------
extern "C" void kernel_launch(void* const* d_in, const int* in_sizes, int n_in,
                              void* d_out, int out_size, void* d_ws, size_t ws_size,
                              hipStream_t stream) {
    const float* X  = (const float*)d_in[0];  // [4096, 2496]
    const float* Mx = (const float*)d_in[1];  // [2048, 2496]
    float* out = (float*)d_out;               // [4096, 2048]

    // Workspace layout (~15.4 MB): Xq u8 | Mq u8 | xsq f32 | msq f32
    unsigned char* Xq = (unsigned char*)d_ws;
    unsigned char* Mq = Xq + (size_t)B_DIM * D_DIM;
    float* xsq = (float*)(Mq + (size_t)S_DIM * D_DIM);
    float* msq = xsq + B_DIM;

    prep_kernel<<<(B_DIM + S_DIM) / 4, 256, 0, stream>>>(X, Mx, Xq, Mq, xsq, msq);

    dim3 grid(512);  // 32 bm x 16 bn via XCD-resident mapping, 2 blocks/CU
    gemm_kernel<<<grid, 256, 0, stream>>>(Xq, Mq, xsq, msq, out);
}